// Round 8
// baseline (3724.529 us; speedup 1.0000x reference)
//
#include <hip/hip_runtime.h>

#define N_NODES 100000
#define N_EDGES 1250000
#define IN_DIM  128
#define HID     64
#define OUTD    16
#define ROW     64                 // padded CSR width (in-deg Poisson(12.5), max ~45)
#define NBUCKET 16                 // dst-range buckets (2 per XCD, processed serially)
#define BSIZE   6250               // nodes per bucket
#define BCAP    90112              // bucket capacity (expected 78125 +- ~300)
#define PARTB   512                // partition blocks
#define NITER_P ((N_EDGES + PARTB * 256 - 1) / (PARTB * 256))   // 10
#define FILL2B  512                // bucket_fill blocks (64 per XCD group)
#define MTILE   128
#define GEMMB   ((N_NODES + MTILE - 1) / MTILE)                 // 782

typedef __attribute__((ext_vector_type(8))) short  short8;   // 8 bf16 (4 VGPRs)
typedef __attribute__((ext_vector_type(4))) float  floatx4;  // MFMA acc

__device__ __forceinline__ unsigned short f2bf(float f) {   // RNE bf16
    unsigned u = __float_as_uint(f);
    u += 0x7fffu + ((u >> 16) & 1u);
    return (unsigned short)(u >> 16);
}
__device__ __forceinline__ float bf2f_lo(unsigned u) { return __uint_as_float(u << 16); }
__device__ __forceinline__ float bf2f_hi(unsigned u) { return __uint_as_float(u & 0xffff0000u); }

// ---------------- init: zero cursor, bucket cursors, dummy hb row ----------
__global__ __launch_bounds__(256) void init_kernel(int* __restrict__ cursor,
                                                   int* __restrict__ bcur,
                                                   unsigned* __restrict__ hb_dummy) {
    int i = blockIdx.x * 256 + threadIdx.x;
    if (i < N_NODES) cursor[i] = 0;
    if (i < NBUCKET) bcur[i] = 0;
    if (i < 32) hb_dummy[i] = 0u;          // 128B zero row (pull pad target)
}

// ---------------- phase 1: partition edges into 16 dst-range buckets -------
// warp-aggregated cursor reservation -> bucket writes are dense/sequential
// (no write amplification). Entry packs src (17b) | dst-local (13b).
__global__ __launch_bounds__(256) void partition_kernel(const int* __restrict__ src,
                                                        const int* __restrict__ dst,
                                                        int* __restrict__ bcur,
                                                        unsigned* __restrict__ bucket) {
    const int lane = threadIdx.x & 63;
    for (int it = 0; it < NITER_P; it++) {
        int e = it * PARTB * 256 + blockIdx.x * 256 + threadIdx.x;
        int r = -1, s = 0, d = 0;
        if (e < N_EDGES) {
            d = dst[e];
            s = src[e];
            r = d / BSIZE;                 // 0..15 (magic-mul)
        }
#pragma unroll 4
        for (int r0 = 0; r0 < NBUCKET; r0++) {
            unsigned long long m = __ballot(r == r0);   // all lanes participate
            if (r == r0) {
                int ldr  = __ffsll((unsigned long long)m) - 1;
                int rank = __popcll(m & ((1ull << lane) - 1ull));
                int base = 0;
                if (lane == ldr) base = atomicAdd(&bcur[r0], (int)__popcll(m));
                base = __shfl(base, ldr, 64);
                int p = base + rank;
                if (p < BCAP)
                    bucket[(size_t)r0 * BCAP + p] =
                        (unsigned)s | ((unsigned)(d - r0 * BSIZE) << 17);
            }
        }
    }
}

// ---------------- phase 2: scatter within L2-resident bucket slice ---------
// 8 XCD groups (blockIdx&7); each group serially processes its 2 buckets.
// csr slice = 6250 nodes x 256B = 1.6MB + 25KB cursor slice: fits one XCD's
// 4MB L2 -> each dirty csr line written back to HBM once.
__global__ __launch_bounds__(256) void bucket_fill(const int* __restrict__ bcur,
                                                   const unsigned* __restrict__ bucket,
                                                   int* __restrict__ cursor,
                                                   int* __restrict__ csr) {
    const int g = blockIdx.x & 7;
    const int j = blockIdx.x >> 3;         // 0..63 within group
    for (int pass = 0; pass < 2; pass++) {
        const int r   = g + pass * 8;
        const int lo  = r * BSIZE;
        const int cnt = min(bcur[r], BCAP);
        const unsigned* bk = bucket + (size_t)r * BCAP;
        for (int idx = j * 256 + threadIdx.x; idx < cnt; idx += (FILL2B / 8) * 256) {
            unsigned v = bk[idx];
            int s = (int)(v & 0x1FFFFu);
            int d = lo + (int)(v >> 17);
            int p = atomicAdd(&cursor[d], 1);
            if (p < ROW) csr[(size_t)d * ROW + p] = s;
        }
    }
}

// ---------------- MFMA gemm: h' = (x @ W1) * dis, bf16 out, M-tile 128 -----
// block = 256 (4 waves); wave w covers rows w*32..w*32+31 x all 64 cols
// (8 MFMA tiles, 32 MFMAs). W1 staged ONCE per 128 rows (vs once per 16).
// +132 row pitch keeps b128 frag reads >=2-way-free.
__global__ __launch_bounds__(256) void gemm_mfma(const float* __restrict__ x,
                                                 const float* __restrict__ W1,
                                                 const int* __restrict__ cursor,
                                                 float* __restrict__ dis,
                                                 unsigned short* __restrict__ hb) {
    __shared__ unsigned short xs[MTILE][132];   // [m][k] bf16
    __shared__ unsigned short w1t[HID][132];    // [n][k] bf16
    const int m0 = blockIdx.x * MTILE;

    for (int q = threadIdx.x; q < MTILE * IN_DIM / 4; q += 256) {
        int m = q >> 5, k4 = q & 31;
        int row = min(m0 + m, N_NODES - 1);
        float4 xq = ((const float4*)(x + (size_t)row * IN_DIM))[k4];
        unsigned short* p = &xs[m][k4 * 4];
        p[0] = f2bf(xq.x); p[1] = f2bf(xq.y); p[2] = f2bf(xq.z); p[3] = f2bf(xq.w);
    }
    for (int q = threadIdx.x; q < IN_DIM * HID / 4; q += 256) {
        int k = q >> 4, n = (q & 15) * 4;
        float4 wq = ((const float4*)W1)[q];
        w1t[n + 0][k] = f2bf(wq.x);
        w1t[n + 1][k] = f2bf(wq.y);
        w1t[n + 2][k] = f2bf(wq.z);
        w1t[n + 3][k] = f2bf(wq.w);
    }
    __syncthreads();

    const int lane = threadIdx.x & 63;
    const int w    = threadIdx.x >> 6;
    const int mrow = lane & 15;
    const int quad = lane >> 4;

    floatx4 acc[2][4] = {};
#pragma unroll
    for (int k0 = 0; k0 < IN_DIM; k0 += 32) {
        short8 a0 = *(const short8*)&xs[w * 32 + mrow     ][k0 + quad * 8];
        short8 a1 = *(const short8*)&xs[w * 32 + 16 + mrow][k0 + quad * 8];
        short8 b0 = *(const short8*)&w1t[ 0 + mrow][k0 + quad * 8];
        short8 b1 = *(const short8*)&w1t[16 + mrow][k0 + quad * 8];
        short8 b2 = *(const short8*)&w1t[32 + mrow][k0 + quad * 8];
        short8 b3 = *(const short8*)&w1t[48 + mrow][k0 + quad * 8];
        acc[0][0] = __builtin_amdgcn_mfma_f32_16x16x32_bf16(a0, b0, acc[0][0], 0, 0, 0);
        acc[0][1] = __builtin_amdgcn_mfma_f32_16x16x32_bf16(a0, b1, acc[0][1], 0, 0, 0);
        acc[0][2] = __builtin_amdgcn_mfma_f32_16x16x32_bf16(a0, b2, acc[0][2], 0, 0, 0);
        acc[0][3] = __builtin_amdgcn_mfma_f32_16x16x32_bf16(a0, b3, acc[0][3], 0, 0, 0);
        acc[1][0] = __builtin_amdgcn_mfma_f32_16x16x32_bf16(a1, b0, acc[1][0], 0, 0, 0);
        acc[1][1] = __builtin_amdgcn_mfma_f32_16x16x32_bf16(a1, b1, acc[1][1], 0, 0, 0);
        acc[1][2] = __builtin_amdgcn_mfma_f32_16x16x32_bf16(a1, b2, acc[1][2], 0, 0, 0);
        acc[1][3] = __builtin_amdgcn_mfma_f32_16x16x32_bf16(a1, b3, acc[1][3], 0, 0, 0);
    }

    // D: row = w*32 + tm*16 + quad*4+reg, col = tn*16 + mrow. dis at store.
#pragma unroll
    for (int tm = 0; tm < 2; tm++) {
#pragma unroll
        for (int reg = 0; reg < 4; reg++) {
            int m = m0 + w * 32 + tm * 16 + quad * 4 + reg;
            if (m < N_NODES) {
                float di = rsqrtf((float)cursor[m] + 1.0f);
#pragma unroll
                for (int tn = 0; tn < 4; tn++)
                    hb[(size_t)m * HID + tn * 16 + mrow] = f2bf(acc[tm][tn][reg] * di);
            }
        }
    }
    if (threadIdx.x < MTILE) {
        int m = m0 + threadIdx.x;
        if (m < N_NODES) dis[m] = rsqrtf((float)cursor[m] + 1.0f);
    }
}

// ------- fused: pull-sum + final scale + bias/relu + W2 + log_softmax ------
// UNCHANGED from R7 (kept identical so its counters stay comparable).
__global__ __launch_bounds__(256) void pull_epilogue(const unsigned short* __restrict__ hb,
                                                     const int* __restrict__ csr,
                                                     const int* __restrict__ deg,
                                                     const float* __restrict__ dis,
                                                     const float* __restrict__ b1,
                                                     const float* __restrict__ W2,
                                                     const float* __restrict__ b2,
                                                     float* __restrict__ out) {
    const int i     = blockIdx.x * 4 + (threadIdx.x >> 6);
    const int lane  = threadIdx.x & 63;
    const int e_sub = lane >> 4;   // 0..3
    const int f4    = lane & 15;   // bf16x4 slot of HID

    const int   cnt = min(deg[i], ROW);
    const float di  = dis[i];

    int s_l = N_NODES;                                    // pad -> dummy zero row
    if (lane < cnt) s_l = csr[(size_t)i * ROW + lane];

    uint2 hs = ((const uint2*)(hb + (size_t)i * HID))[f4];  // self slice (h'_i)

    float ax = 0.f, ay = 0.f, az = 0.f, aw = 0.f;
    const int G = (cnt + 3) >> 2;
    int g = 0;
    for (; g + 2 <= G; g += 2) {
        int e0 = (g << 2) + e_sub, e1 = e0 + 4;
        int s0 = __shfl(s_l, e0, 64), s1 = __shfl(s_l, e1, 64);
        uint2 a = ((const uint2*)(hb + (size_t)s0 * HID))[f4];
        uint2 b = ((const uint2*)(hb + (size_t)s1 * HID))[f4];
        ax += bf2f_lo(a.x); ay += bf2f_hi(a.x); az += bf2f_lo(a.y); aw += bf2f_hi(a.y);
        ax += bf2f_lo(b.x); ay += bf2f_hi(b.x); az += bf2f_lo(b.y); aw += bf2f_hi(b.y);
    }
    if (g < G) {
        int e0 = (g << 2) + e_sub;
        int s0 = __shfl(s_l, e0, 64);
        uint2 a = ((const uint2*)(hb + (size_t)s0 * HID))[f4];
        ax += bf2f_lo(a.x); ay += bf2f_hi(a.x); az += bf2f_lo(a.y); aw += bf2f_hi(a.y);
    }

    ax += __shfl_xor(ax, 16, 64); ax += __shfl_xor(ax, 32, 64);
    ay += __shfl_xor(ay, 16, 64); ay += __shfl_xor(ay, 32, 64);
    az += __shfl_xor(az, 16, 64); az += __shfl_xor(az, 32, 64);
    aw += __shfl_xor(aw, 16, 64); aw += __shfl_xor(aw, 32, 64);

    float4 b1v = ((const float4*)b1)[f4];
    float v0 = fmaxf(fmaf(ax + bf2f_lo(hs.x), di, b1v.x), 0.f);
    float v1 = fmaxf(fmaf(ay + bf2f_hi(hs.x), di, b1v.y), 0.f);
    float v2 = fmaxf(fmaf(az + bf2f_lo(hs.y), di, b1v.z), 0.f);
    float v3 = fmaxf(fmaf(aw + bf2f_hi(hs.y), di, b1v.w), 0.f);

    const float4* W2v = (const float4*)W2;         // [HID][OUTD/4] float4 view
    float4 w0 = W2v[(4 * f4 + 0) * 4 + e_sub];
    float4 w1 = W2v[(4 * f4 + 1) * 4 + e_sub];
    float4 w2 = W2v[(4 * f4 + 2) * 4 + e_sub];
    float4 w3 = W2v[(4 * f4 + 3) * 4 + e_sub];
    float p0 = v0 * w0.x + v1 * w1.x + v2 * w2.x + v3 * w3.x;
    float p1 = v0 * w0.y + v1 * w1.y + v2 * w2.y + v3 * w3.y;
    float p2 = v0 * w0.z + v1 * w1.z + v2 * w2.z + v3 * w3.z;
    float p3 = v0 * w0.w + v1 * w1.w + v2 * w2.w + v3 * w3.w;
#pragma unroll
    for (int d = 1; d < 16; d <<= 1) {
        p0 += __shfl_xor(p0, d, 64);
        p1 += __shfl_xor(p1, d, 64);
        p2 += __shfl_xor(p2, d, 64);
        p3 += __shfl_xor(p3, d, 64);
    }
    float4 b2v = ((const float4*)b2)[e_sub];
    float lg0 = p0 + b2v.x, lg1 = p1 + b2v.y, lg2 = p2 + b2v.z, lg3 = p3 + b2v.w;

    float m = fmaxf(fmaxf(lg0, lg1), fmaxf(lg2, lg3));
    m = fmaxf(m, __shfl_xor(m, 16, 64));
    m = fmaxf(m, __shfl_xor(m, 32, 64));
    float s = __expf(lg0 - m) + __expf(lg1 - m) + __expf(lg2 - m) + __expf(lg3 - m);
    s += __shfl_xor(s, 16, 64);
    s += __shfl_xor(s, 32, 64);
    float lse = __logf(s) + m;

    if (f4 == 0) {
        float4 o = make_float4(lg0 - lse, lg1 - lse, lg2 - lse, lg3 - lse);
        ((float4*)out)[(size_t)i * 4 + e_sub] = o;
    }
}

extern "C" void kernel_launch(void* const* d_in, const int* in_sizes, int n_in,
                              void* d_out, int out_size, void* d_ws, size_t ws_size,
                              hipStream_t stream) {
    const float* x   = (const float*)d_in[0];
    const int*   ei  = (const int*)d_in[1];    // int64 in ref -> int32 here
    const float* W1  = (const float*)d_in[2];
    const float* b1  = (const float*)d_in[3];
    const float* W2  = (const float*)d_in[4];
    const float* b2  = (const float*)d_in[5];
    float*       out = (float*)d_out;

    const int* src = ei;             // edge_index[0]
    const int* dst = ei + N_EDGES;   // edge_index[1]

    char* ws = (char*)d_ws;
    size_t off = 0;
    unsigned short* hb = (unsigned short*)(ws + off);
    off += (size_t)(N_NODES + 1) * HID * 2;                                       // 12.8 MB
    int*      csr    = (int*)     (ws + off); off += ((size_t)N_NODES * ROW + ROW) * 4; // 25.6 MB
    int*      cursor = (int*)     (ws + off); off += (size_t)N_NODES * 4;         // 400 KB
    float*    dis    = (float*)   (ws + off); off += (size_t)N_NODES * 4;         // 400 KB
    int*      bcur   = (int*)     (ws + off); off += 256;
    unsigned* bucket = (unsigned*)(ws + off); off += (size_t)NBUCKET * BCAP * 4;  // 5.8 MB

    init_kernel<<<(N_NODES + 255) / 256, 256, 0, stream>>>(
        cursor, bcur, (unsigned*)(hb + (size_t)N_NODES * HID));
    partition_kernel<<<PARTB, 256, 0, stream>>>(src, dst, bcur, bucket);
    bucket_fill<<<FILL2B, 256, 0, stream>>>(bcur, bucket, cursor, csr);
    gemm_mfma<<<GEMMB, 256, 0, stream>>>(x, W1, cursor, dis, hb);
    pull_epilogue<<<N_NODES / 4, 256, 0, stream>>>(hb, csr, cursor, dis, b1, W2, b2, out);
}

// Round 9
// 250.687 us; speedup vs baseline: 14.8573x; 14.8573x over previous
//
#include <hip/hip_runtime.h>

#define N_NODES 100000
#define N_EDGES 1250000
#define IN_DIM  128
#define HID     64
#define OUTD    16
#define ROW     64                 // padded CSR width (in-deg Poisson(12.5), max ~45)
#define NBUCKET 16                 // dst-range buckets (2 per XCD, processed serially)
#define BSIZE   6250               // nodes per bucket
#define BCAP    90112              // bucket capacity (expected 78125 +- ~300)
#define PARTB   512                // partition blocks
#define CHUNK_P ((N_EDGES + PARTB - 1) / PARTB)                 // 2442
#define FILL2B  512                // bucket_fill blocks (64 per XCD group)
#define MTILE   128
#define GEMMB   ((N_NODES + MTILE - 1) / MTILE)                 // 782

typedef __attribute__((ext_vector_type(8))) short  short8;   // 8 bf16 (4 VGPRs)
typedef __attribute__((ext_vector_type(4))) float  floatx4;  // MFMA acc

__device__ __forceinline__ unsigned short f2bf(float f) {   // RNE bf16
    unsigned u = __float_as_uint(f);
    u += 0x7fffu + ((u >> 16) & 1u);
    return (unsigned short)(u >> 16);
}
__device__ __forceinline__ float bf2f_lo(unsigned u) { return __uint_as_float(u << 16); }
__device__ __forceinline__ float bf2f_hi(unsigned u) { return __uint_as_float(u & 0xffff0000u); }

// ---------------- init: zero cursor, bucket cursors (64B-padded), dummy ----
__global__ __launch_bounds__(256) void init_kernel(int* __restrict__ cursor,
                                                   int* __restrict__ bcur,
                                                   unsigned* __restrict__ hb_dummy) {
    int i = blockIdx.x * 256 + threadIdx.x;
    if (i < N_NODES) cursor[i] = 0;
    if (i < NBUCKET * 16) bcur[i] = 0;     // one counter per 64B line
    if (i < 32) hb_dummy[i] = 0u;          // 128B zero row (pull pad target)
}

// ---------------- phase 1: partition edges into 16 dst-range buckets -------
// Block-local two-pass: LDS histogram -> 16 global atomics per block on
// 64B-padded counters (no shared hot line!) -> dense segment writes.
// Entry packs src (17b) | dst-local (13b).
__global__ __launch_bounds__(256) void partition_kernel(const int* __restrict__ src,
                                                        const int* __restrict__ dst,
                                                        int* __restrict__ bcur,
                                                        unsigned* __restrict__ bucket) {
    __shared__ int lcnt[NBUCKET];
    __shared__ int lbase[NBUCKET];
    const int t  = threadIdx.x;
    const int e0 = blockIdx.x * CHUNK_P;
    const int e1 = min(N_EDGES, e0 + CHUNK_P);

    if (t < NBUCKET) lcnt[t] = 0;
    __syncthreads();
    for (int e = e0 + t; e < e1; e += 256)
        atomicAdd(&lcnt[dst[e] / BSIZE], 1);          // LDS atomic, cheap
    __syncthreads();
    if (t < NBUCKET) {
        lbase[t] = atomicAdd(&bcur[t * 16], lcnt[t]); // 16 global atomics/block
        lcnt[t]  = 0;                                 // reuse as local cursor
    }
    __syncthreads();
    for (int e = e0 + t; e < e1; e += 256) {          // chunk is L1/L2-hot
        int d = dst[e];
        int s = src[e];
        int r = d / BSIZE;
        int p = lbase[r] + atomicAdd(&lcnt[r], 1);
        if (p < BCAP)
            bucket[(size_t)r * BCAP + p] = (unsigned)s | ((unsigned)(d - r * BSIZE) << 17);
    }
}

// ---------------- phase 2: scatter within L2-resident bucket slice ---------
// 8 XCD groups (blockIdx&7); each group serially processes its 2 buckets.
// csr slice = 6250 nodes x 256B = 1.6MB + 25KB cursor slice: fits one XCD's
// 4MB L2 -> each dirty csr line written back to HBM once.
__global__ __launch_bounds__(256) void bucket_fill(const int* __restrict__ bcur,
                                                   const unsigned* __restrict__ bucket,
                                                   int* __restrict__ cursor,
                                                   int* __restrict__ csr) {
    const int g = blockIdx.x & 7;
    const int j = blockIdx.x >> 3;         // 0..63 within group
    for (int pass = 0; pass < 2; pass++) {
        const int r   = g + pass * 8;
        const int lo  = r * BSIZE;
        const int cnt = min(bcur[r * 16], BCAP);
        const unsigned* bk = bucket + (size_t)r * BCAP;
        for (int idx = j * 256 + threadIdx.x; idx < cnt; idx += (FILL2B / 8) * 256) {
            unsigned v = bk[idx];
            int s = (int)(v & 0x1FFFFu);
            int d = lo + (int)(v >> 17);
            int p = atomicAdd(&cursor[d], 1);
            if (p < ROW) csr[(size_t)d * ROW + p] = s;
        }
    }
}

// ---------------- MFMA gemm: h' = (x @ W1) * dis, bf16 out, M-tile 128 -----
// UNCHANGED from R8.
__global__ __launch_bounds__(256) void gemm_mfma(const float* __restrict__ x,
                                                 const float* __restrict__ W1,
                                                 const int* __restrict__ cursor,
                                                 float* __restrict__ dis,
                                                 unsigned short* __restrict__ hb) {
    __shared__ unsigned short xs[MTILE][132];   // [m][k] bf16
    __shared__ unsigned short w1t[HID][132];    // [n][k] bf16
    const int m0 = blockIdx.x * MTILE;

    for (int q = threadIdx.x; q < MTILE * IN_DIM / 4; q += 256) {
        int m = q >> 5, k4 = q & 31;
        int row = min(m0 + m, N_NODES - 1);
        float4 xq = ((const float4*)(x + (size_t)row * IN_DIM))[k4];
        unsigned short* p = &xs[m][k4 * 4];
        p[0] = f2bf(xq.x); p[1] = f2bf(xq.y); p[2] = f2bf(xq.z); p[3] = f2bf(xq.w);
    }
    for (int q = threadIdx.x; q < IN_DIM * HID / 4; q += 256) {
        int k = q >> 4, n = (q & 15) * 4;
        float4 wq = ((const float4*)W1)[q];
        w1t[n + 0][k] = f2bf(wq.x);
        w1t[n + 1][k] = f2bf(wq.y);
        w1t[n + 2][k] = f2bf(wq.z);
        w1t[n + 3][k] = f2bf(wq.w);
    }
    __syncthreads();

    const int lane = threadIdx.x & 63;
    const int w    = threadIdx.x >> 6;
    const int mrow = lane & 15;
    const int quad = lane >> 4;

    floatx4 acc[2][4] = {};
#pragma unroll
    for (int k0 = 0; k0 < IN_DIM; k0 += 32) {
        short8 a0 = *(const short8*)&xs[w * 32 + mrow     ][k0 + quad * 8];
        short8 a1 = *(const short8*)&xs[w * 32 + 16 + mrow][k0 + quad * 8];
        short8 b0 = *(const short8*)&w1t[ 0 + mrow][k0 + quad * 8];
        short8 b1 = *(const short8*)&w1t[16 + mrow][k0 + quad * 8];
        short8 b2 = *(const short8*)&w1t[32 + mrow][k0 + quad * 8];
        short8 b3 = *(const short8*)&w1t[48 + mrow][k0 + quad * 8];
        acc[0][0] = __builtin_amdgcn_mfma_f32_16x16x32_bf16(a0, b0, acc[0][0], 0, 0, 0);
        acc[0][1] = __builtin_amdgcn_mfma_f32_16x16x32_bf16(a0, b1, acc[0][1], 0, 0, 0);
        acc[0][2] = __builtin_amdgcn_mfma_f32_16x16x32_bf16(a0, b2, acc[0][2], 0, 0, 0);
        acc[0][3] = __builtin_amdgcn_mfma_f32_16x16x32_bf16(a0, b3, acc[0][3], 0, 0, 0);
        acc[1][0] = __builtin_amdgcn_mfma_f32_16x16x32_bf16(a1, b0, acc[1][0], 0, 0, 0);
        acc[1][1] = __builtin_amdgcn_mfma_f32_16x16x32_bf16(a1, b1, acc[1][1], 0, 0, 0);
        acc[1][2] = __builtin_amdgcn_mfma_f32_16x16x32_bf16(a1, b2, acc[1][2], 0, 0, 0);
        acc[1][3] = __builtin_amdgcn_mfma_f32_16x16x32_bf16(a1, b3, acc[1][3], 0, 0, 0);
    }

#pragma unroll
    for (int tm = 0; tm < 2; tm++) {
#pragma unroll
        for (int reg = 0; reg < 4; reg++) {
            int m = m0 + w * 32 + tm * 16 + quad * 4 + reg;
            if (m < N_NODES) {
                float di = rsqrtf((float)cursor[m] + 1.0f);
#pragma unroll
                for (int tn = 0; tn < 4; tn++)
                    hb[(size_t)m * HID + tn * 16 + mrow] = f2bf(acc[tm][tn][reg] * di);
            }
        }
    }
    if (threadIdx.x < MTILE) {
        int m = m0 + threadIdx.x;
        if (m < N_NODES) dis[m] = rsqrtf((float)cursor[m] + 1.0f);
    }
}

// ------- fused: pull-sum + final scale + bias/relu + W2 + log_softmax ------
// UNCHANGED from R7/R8.
__global__ __launch_bounds__(256) void pull_epilogue(const unsigned short* __restrict__ hb,
                                                     const int* __restrict__ csr,
                                                     const int* __restrict__ deg,
                                                     const float* __restrict__ dis,
                                                     const float* __restrict__ b1,
                                                     const float* __restrict__ W2,
                                                     const float* __restrict__ b2,
                                                     float* __restrict__ out) {
    const int i     = blockIdx.x * 4 + (threadIdx.x >> 6);
    const int lane  = threadIdx.x & 63;
    const int e_sub = lane >> 4;   // 0..3
    const int f4    = lane & 15;   // bf16x4 slot of HID

    const int   cnt = min(deg[i], ROW);
    const float di  = dis[i];

    int s_l = N_NODES;                                    // pad -> dummy zero row
    if (lane < cnt) s_l = csr[(size_t)i * ROW + lane];

    uint2 hs = ((const uint2*)(hb + (size_t)i * HID))[f4];  // self slice (h'_i)

    float ax = 0.f, ay = 0.f, az = 0.f, aw = 0.f;
    const int G = (cnt + 3) >> 2;
    int g = 0;
    for (; g + 2 <= G; g += 2) {
        int e0 = (g << 2) + e_sub, e1 = e0 + 4;
        int s0 = __shfl(s_l, e0, 64), s1 = __shfl(s_l, e1, 64);
        uint2 a = ((const uint2*)(hb + (size_t)s0 * HID))[f4];
        uint2 b = ((const uint2*)(hb + (size_t)s1 * HID))[f4];
        ax += bf2f_lo(a.x); ay += bf2f_hi(a.x); az += bf2f_lo(a.y); aw += bf2f_hi(a.y);
        ax += bf2f_lo(b.x); ay += bf2f_hi(b.x); az += bf2f_lo(b.y); aw += bf2f_hi(b.y);
    }
    if (g < G) {
        int e0 = (g << 2) + e_sub;
        int s0 = __shfl(s_l, e0, 64);
        uint2 a = ((const uint2*)(hb + (size_t)s0 * HID))[f4];
        ax += bf2f_lo(a.x); ay += bf2f_hi(a.x); az += bf2f_lo(a.y); aw += bf2f_hi(a.y);
    }

    ax += __shfl_xor(ax, 16, 64); ax += __shfl_xor(ax, 32, 64);
    ay += __shfl_xor(ay, 16, 64); ay += __shfl_xor(ay, 32, 64);
    az += __shfl_xor(az, 16, 64); az += __shfl_xor(az, 32, 64);
    aw += __shfl_xor(aw, 16, 64); aw += __shfl_xor(aw, 32, 64);

    float4 b1v = ((const float4*)b1)[f4];
    float v0 = fmaxf(fmaf(ax + bf2f_lo(hs.x), di, b1v.x), 0.f);
    float v1 = fmaxf(fmaf(ay + bf2f_hi(hs.x), di, b1v.y), 0.f);
    float v2 = fmaxf(fmaf(az + bf2f_lo(hs.y), di, b1v.z), 0.f);
    float v3 = fmaxf(fmaf(aw + bf2f_hi(hs.y), di, b1v.w), 0.f);

    const float4* W2v = (const float4*)W2;         // [HID][OUTD/4] float4 view
    float4 w0 = W2v[(4 * f4 + 0) * 4 + e_sub];
    float4 w1 = W2v[(4 * f4 + 1) * 4 + e_sub];
    float4 w2 = W2v[(4 * f4 + 2) * 4 + e_sub];
    float4 w3 = W2v[(4 * f4 + 3) * 4 + e_sub];
    float p0 = v0 * w0.x + v1 * w1.x + v2 * w2.x + v3 * w3.x;
    float p1 = v0 * w0.y + v1 * w1.y + v2 * w2.y + v3 * w3.y;
    float p2 = v0 * w0.z + v1 * w1.z + v2 * w2.z + v3 * w3.z;
    float p3 = v0 * w0.w + v1 * w1.w + v2 * w2.w + v3 * w3.w;
#pragma unroll
    for (int d = 1; d < 16; d <<= 1) {
        p0 += __shfl_xor(p0, d, 64);
        p1 += __shfl_xor(p1, d, 64);
        p2 += __shfl_xor(p2, d, 64);
        p3 += __shfl_xor(p3, d, 64);
    }
    float4 b2v = ((const float4*)b2)[e_sub];
    float lg0 = p0 + b2v.x, lg1 = p1 + b2v.y, lg2 = p2 + b2v.z, lg3 = p3 + b2v.w;

    float m = fmaxf(fmaxf(lg0, lg1), fmaxf(lg2, lg3));
    m = fmaxf(m, __shfl_xor(m, 16, 64));
    m = fmaxf(m, __shfl_xor(m, 32, 64));
    float s = __expf(lg0 - m) + __expf(lg1 - m) + __expf(lg2 - m) + __expf(lg3 - m);
    s += __shfl_xor(s, 16, 64);
    s += __shfl_xor(s, 32, 64);
    float lse = __logf(s) + m;

    if (f4 == 0) {
        float4 o = make_float4(lg0 - lse, lg1 - lse, lg2 - lse, lg3 - lse);
        ((float4*)out)[(size_t)i * 4 + e_sub] = o;
    }
}

extern "C" void kernel_launch(void* const* d_in, const int* in_sizes, int n_in,
                              void* d_out, int out_size, void* d_ws, size_t ws_size,
                              hipStream_t stream) {
    const float* x   = (const float*)d_in[0];
    const int*   ei  = (const int*)d_in[1];    // int64 in ref -> int32 here
    const float* W1  = (const float*)d_in[2];
    const float* b1  = (const float*)d_in[3];
    const float* W2  = (const float*)d_in[4];
    const float* b2  = (const float*)d_in[5];
    float*       out = (float*)d_out;

    const int* src = ei;             // edge_index[0]
    const int* dst = ei + N_EDGES;   // edge_index[1]

    char* ws = (char*)d_ws;
    size_t off = 0;
    unsigned short* hb = (unsigned short*)(ws + off);
    off += (size_t)(N_NODES + 1) * HID * 2;                                       // 12.8 MB
    int*      csr    = (int*)     (ws + off); off += ((size_t)N_NODES * ROW + ROW) * 4; // 25.6 MB
    int*      cursor = (int*)     (ws + off); off += (size_t)N_NODES * 4;         // 400 KB
    float*    dis    = (float*)   (ws + off); off += (size_t)N_NODES * 4;         // 400 KB
    int*      bcur   = (int*)     (ws + off); off += NBUCKET * 16 * 4;            // padded
    unsigned* bucket = (unsigned*)(ws + off); off += (size_t)NBUCKET * BCAP * 4;  // 5.8 MB

    init_kernel<<<(N_NODES + 255) / 256, 256, 0, stream>>>(
        cursor, bcur, (unsigned*)(hb + (size_t)N_NODES * HID));
    partition_kernel<<<PARTB, 256, 0, stream>>>(src, dst, bcur, bucket);
    bucket_fill<<<FILL2B, 256, 0, stream>>>(bcur, bucket, cursor, csr);
    gemm_mfma<<<GEMMB, 256, 0, stream>>>(x, W1, cursor, dis, hb);
    pull_epilogue<<<N_NODES / 4, 256, 0, stream>>>(hb, csr, cursor, dis, b1, W2, b2, out);
}